// Round 12
// baseline (257.629 us; speedup 1.0000x reference)
//
#include <hip/hip_runtime.h>
#include <hip/hip_bf16.h>

#define NN 16384
#define NHID 256
#define NIN 128
#define NEMB 128
#define NE 262144
#define CAP 56   /* fixed neighbor capacity; P(overflow) ~ 1e-11 */

typedef short short8 __attribute__((ext_vector_type(8)));
typedef unsigned short ushort8 __attribute__((ext_vector_type(8)));
typedef float f32x4 __attribute__((ext_vector_type(4)));

__device__ __forceinline__ float b2f(unsigned short u) {
    return __uint_as_float(((unsigned)u) << 16);
}
__device__ __forceinline__ unsigned short f2b(float f) {
    __hip_bfloat16 h = __float2bfloat16(f);
    return *(unsigned short*)&h;
}
__device__ __forceinline__ unsigned pk2(float lo, float hi) {
    return ((unsigned)f2b(hi) << 16) | (unsigned)f2b(lo);
}
__device__ __forceinline__ bool detect_i64(const int* __restrict__ ei) {
    int any = 0;
    #pragma unroll
    for (int q = 0; q < 32; q++) any |= ei[2*q + 1];
    return any == 0;     // int64 layout: high words of first 32 entries all zero
}

// ---------------- weights -> bf16 transposed WbT[n][k] (one-time, 262144 elems) ----------------

__global__ __launch_bounds__(256) void k_w2bT(const float* __restrict__ W_in,
                                              const float* __restrict__ conv_W,
                                              const float* __restrict__ W_out,
                                              unsigned short* __restrict__ wbt) {
    int id = blockIdx.x * 256 + threadIdx.x;
    unsigned short* wbt_in   = wbt;                    // [256][128]
    unsigned short* wbt_conv = wbt + 32768;            // 3 x [256][256]
    unsigned short* wbt_out  = wbt + 32768 + 196608;   // [128][256]
    if (id < 32768) {              // W_in [128][256]
        int k = id >> 8, n = id & 255;
        wbt_in[n * NIN + k] = f2b(W_in[id]);
    } else if (id < 229376) {      // conv_W [3][256][256]
        int id2 = id - 32768;
        int l = id2 >> 16, r = id2 & 65535;
        int k = r >> 8, n = r & 255;
        wbt_conv[l * 65536 + n * NHID + k] = f2b(conv_W[id2]);
    } else {                       // W_out [256][128]
        int id2 = id - 229376;
        int k = id2 >> 7, n = id2 & 127;
        wbt_out[n * NHID + k] = f2b(W_out[id2]);
    }
}

// ---------------- graph build: fixed-capacity rows, slot = atomicAdd(deg) ----------------

__global__ void k_fill(const int* __restrict__ ei, int* __restrict__ deg,
                       unsigned short* __restrict__ cols) {
    bool i64 = detect_i64(ei);
    int e = blockIdx.x * 256 + threadIdx.x;
    if (e < NN) {
        int p = atomicAdd(&deg[e], 1);
        if (p < CAP) cols[e * CAP + p] = (unsigned short)e;
    }
    if (e >= NE) return;
    int r, c;
    if (i64) { r = ei[2*e]; c = ei[2*(NE + e)]; }
    else     { r = ei[e];   c = ei[NE + e]; }
    int p = atomicAdd(&deg[r], 1);
    if (p < CAP) cols[r * CAP + p] = (unsigned short)c;
}

// wave per row: in-register 64-lane bitonic sort + ballot compaction (proven R9-R11)
__global__ __launch_bounds__(256) void k_dedup(const int* __restrict__ deg,
                                               unsigned short* __restrict__ cols,
                                               int* __restrict__ udeg,
                                               float* __restrict__ dis) {
    int lane = threadIdx.x & 63;
    int row = (blockIdx.x * 256 + threadIdx.x) >> 6;
    int s = row * CAP;
    int L = deg[row]; if (L > CAP) L = CAP;
    int v = (lane < L) ? (int)cols[s + lane] : 0x7fffffff;
    #pragma unroll
    for (int k = 2; k <= 64; k <<= 1) {
        #pragma unroll
        for (int j = k >> 1; j > 0; j >>= 1) {
            int p = __shfl_xor(v, j);
            bool up = ((lane & k) == 0);
            bool keepmin = (((lane & j) == 0) == up);
            int lo = v < p ? v : p, hi = v < p ? p : v;
            v = keepmin ? lo : hi;
        }
    }
    int prev = __shfl_up(v, 1);
    bool keep = (lane < L) && !(lane > 0 && v == prev);
    unsigned long long km = __ballot(keep);
    int u = __popcll(km);
    int pre = __popcll(km & ((1ull << lane) - 1ull));
    if (keep) cols[s + pre] = (unsigned short)v;
    if (lane == 0) {
        udeg[row] = u;
        dis[row] = 1.0f / sqrtf((float)u + 1e-8f);
    }
}

// ---------------- SpMM: 2 neighbors/iter, 16B/lane, shfl_xor(32) combine ----------------

__global__ __launch_bounds__(256) void k_spmm_b(const unsigned short* __restrict__ h,
                                                const int* __restrict__ udeg,
                                                const unsigned short* __restrict__ cols,
                                                const float* __restrict__ dis,
                                                unsigned short* __restrict__ outb) {
    int row = (blockIdx.x * 256 + threadIdx.x) >> 6;
    int lane = threadIdx.x & 63;
    int half = lane >> 5, l32 = lane & 31;
    int s = row * CAP, L = udeg[row];
    float a[8] = {0.f, 0.f, 0.f, 0.f, 0.f, 0.f, 0.f, 0.f};
    for (int k = half; k < L; k += 2) {
        int j = cols[s + k];
        float sc = dis[j];
        ushort8 v = *(const ushort8*)&h[(size_t)j * NHID + l32 * 8];
        #pragma unroll
        for (int c = 0; c < 8; c++) a[c] += sc * b2f(v[c]);
    }
    #pragma unroll
    for (int c = 0; c < 8; c++) a[c] += __shfl_xor(a[c], 32);
    if (half == 0) {
        float sr = dis[row];
        ushort8 o;
        #pragma unroll
        for (int c = 0; c < 8; c++) o[c] = f2b(a[c] * sr);
        *(ushort8*)&outb[(size_t)row * NHID + l32 * 8] = o;
    }
}

// ---------------- MFMA bf16 GEMM, block 64 x C, optional fused LayerNorm ----------------
// 4 waves side-by-side in cols: wave w = 64 rows x C/4 cols, NTW = C/64 n-frags.
// B from pre-transposed bf16 WbT[n][k]: staging = pure uint4 copies (no cvt VALU).
// K-step prefetch: next step's global loads issue before current MFMA section.
// LN=1 (requires C==256): full row in block; stats via 16-lane shfl_xor + LDS
// cross-wave combine; epilogue writes (v-mean)*rstd*g+b. Stats on fp32 v
// (pre-bf16-rounding), matching reference LN placement.
// mfma_f32_16x16x32_bf16 layouts m89-verified (see R8).

template<int C, int AF32, int LEAKY, int RES, int LN, int OUTF32>
__global__ __launch_bounds__(256) void k_gemm_mfma(
        const unsigned short* __restrict__ Ab, const float* __restrict__ Af,
        const unsigned short* __restrict__ Wb,
        const float* __restrict__ bias, const unsigned short* __restrict__ res,
        const float* __restrict__ g, const float* __restrict__ bln,
        float* __restrict__ outf, unsigned short* __restrict__ outb,
        int K) {
    constexpr int NTW = C / 64;              // n-frags per wave
    __shared__ unsigned short As[64 * 40];
    __shared__ unsigned short Bs[C * 40];
    __shared__ float sm_s[4][64], sm_q[4][64];
    int t = threadIdx.x;
    int lane = t & 63;
    int w = t >> 6;
    int bm0 = blockIdx.x * 64, bn0 = blockIdx.y * C;
    int lrow = lane & 15, lk8 = (lane >> 4) * 8;

    int ar = t >> 2, akq = (t & 3) * 8;      // A staging: row 0..63, 8-elem quarter
    int bcol = (C == 256) ? t : (t >> 1);    // B staging col
    int bkh  = (C == 256) ? 0 : (t & 1) * 16;

    uint4 aq;
    float4 xa0, xa1;
    uint4 bq[(C == 256) ? 4 : 2];

    auto loadg = [&](int k0) {
        if (AF32) {
            const float* asrc = Af + (size_t)(bm0 + ar) * K + k0 + akq;
            xa0 = *(const float4*)(asrc + 0);
            xa1 = *(const float4*)(asrc + 4);
        } else {
            aq = *(const uint4*)(Ab + (size_t)(bm0 + ar) * K + k0 + akq);
        }
        const unsigned short* bsrc = Wb + (size_t)(bn0 + bcol) * K + k0 + bkh;
        #pragma unroll
        for (int q = 0; q < ((C == 256) ? 4 : 2); q++)
            bq[q] = *(const uint4*)(bsrc + q * 8);
    };

    f32x4 acc[4][NTW];
    #pragma unroll
    for (int m = 0; m < 4; m++)
        #pragma unroll
        for (int n = 0; n < NTW; n++) acc[m][n] = (f32x4){0.f, 0.f, 0.f, 0.f};

    loadg(0);
    for (int k0 = 0; k0 < K; k0 += 32) {
        __syncthreads();                     // prior compute done before overwrite
        if (AF32) {
            unsigned* dst = (unsigned*)&As[ar * 40 + akq];
            dst[0] = pk2(xa0.x, xa0.y); dst[1] = pk2(xa0.z, xa0.w);
            dst[2] = pk2(xa1.x, xa1.y); dst[3] = pk2(xa1.z, xa1.w);
        } else {
            *(uint4*)&As[ar * 40 + akq] = aq;
        }
        #pragma unroll
        for (int q = 0; q < ((C == 256) ? 4 : 2); q++)
            *(uint4*)&Bs[bcol * 40 + bkh + q * 8] = bq[q];
        __syncthreads();
        if (k0 + 32 < K) loadg(k0 + 32);     // prefetch next step under compute
        short8 bf[NTW];
        #pragma unroll
        for (int n = 0; n < NTW; n++)
            bf[n] = *(const short8*)&Bs[(w * (C / 4) + n * 16 + lrow) * 40 + lk8];
        #pragma unroll
        for (int m = 0; m < 4; m++) {
            short8 af = *(const short8*)&As[(m * 16 + lrow) * 40 + lk8];
            #pragma unroll
            for (int n = 0; n < NTW; n++)
                acc[m][n] = __builtin_amdgcn_mfma_f32_16x16x32_bf16(af, bf[n], acc[m][n], 0, 0, 0);
        }
    }

    // ---- epilogue: bias + leaky + residual (stored back into acc) ----
    float bias_c[NTW];
    #pragma unroll
    for (int n = 0; n < NTW; n++) bias_c[n] = bias[bn0 + w * (C / 4) + n * 16 + lrow];

    #pragma unroll
    for (int m = 0; m < 4; m++) {
        #pragma unroll
        for (int n = 0; n < NTW; n++) {
            int col = bn0 + w * (C / 4) + n * 16 + lrow;
            #pragma unroll
            for (int i = 0; i < 4; i++) {
                int row = bm0 + m * 16 + (lane >> 4) * 4 + i;
                float v = acc[m][n][i] + bias_c[n];
                if (LEAKY) v = v > 0.f ? v : 0.2f * v;
                if (RES) v += b2f(res[(size_t)row * C + col - bn0 + (size_t)bn0]);
                acc[m][n][i] = v;
            }
        }
    }

    if (LN) {   // C == 256: full row in block
        #pragma unroll
        for (int m = 0; m < 4; m++) {
            #pragma unroll
            for (int i = 0; i < 4; i++) {
                float p = 0.f, q = 0.f;
                #pragma unroll
                for (int n = 0; n < NTW; n++) { float v = acc[m][n][i]; p += v; q += v * v; }
                #pragma unroll
                for (int off = 1; off < 16; off <<= 1) {
                    p += __shfl_xor(p, off);
                    q += __shfl_xor(q, off);
                }
                if ((lane & 15) == 0) {
                    int rl = m * 16 + (lane >> 4) * 4 + i;
                    sm_s[w][rl] = p; sm_q[w][rl] = q;
                }
            }
        }
        __syncthreads();
        float gg[NTW], bb[NTW];
        #pragma unroll
        for (int n = 0; n < NTW; n++) {
            int col = w * (C / 4) + n * 16 + lrow;
            gg[n] = g[col]; bb[n] = bln[col];
        }
        #pragma unroll
        for (int m = 0; m < 4; m++) {
            #pragma unroll
            for (int i = 0; i < 4; i++) {
                int rl = m * 16 + (lane >> 4) * 4 + i;
                float S = sm_s[0][rl] + sm_s[1][rl] + sm_s[2][rl] + sm_s[3][rl];
                float Q = sm_q[0][rl] + sm_q[1][rl] + sm_q[2][rl] + sm_q[3][rl];
                float mean = S * (1.0f / 256.0f);
                float var = Q * (1.0f / 256.0f) - mean * mean;
                float rstd = 1.0f / sqrtf(var + 1e-5f);
                int row = bm0 + rl;
                #pragma unroll
                for (int n = 0; n < NTW; n++) {
                    int col = w * (C / 4) + n * 16 + lrow;
                    float val = (acc[m][n][i] - mean) * rstd * gg[n] + bb[n];
                    outb[(size_t)row * C + col] = f2b(val);
                }
            }
        }
    } else {
        #pragma unroll
        for (int m = 0; m < 4; m++) {
            #pragma unroll
            for (int n = 0; n < NTW; n++) {
                int col = bn0 + w * (C / 4) + n * 16 + lrow;
                #pragma unroll
                for (int i = 0; i < 4; i++) {
                    int row = bm0 + m * 16 + (lane >> 4) * 4 + i;
                    float v = acc[m][n][i];
                    if (OUTF32) outf[(size_t)row * ((C == 128) ? NEMB : NHID) + col] = v;
                    else        outb[(size_t)row * ((C == 128) ? NEMB : NHID) + col] = f2b(v);
                }
            }
        }
    }
}

// ---------------- launch ----------------
// ws layout (~18.6 MB): deg @0 (64K), udeg @64K, dis @128K, cols @192K (1.75 MB),
//   WbT @2MB (512 KB), hA @2.5MB (8 MB) -> 10.5MB, tbuf @10.5MB (8 MB) -> 18.5MB.
//   hB = d_out as bf16 scratch; final GEMM reads hA, writes d_out fp32.

extern "C" void kernel_launch(void* const* d_in, const int* in_sizes, int n_in,
                              void* d_out, int out_size, void* d_ws, size_t ws_size,
                              hipStream_t stream) {
    const float* x      = (const float*)d_in[0];
    const int*   ei     = (const int*)  d_in[1];
    const float* W_in   = (const float*)d_in[2];
    const float* b_in   = (const float*)d_in[3];
    const float* conv_W = (const float*)d_in[4];
    const float* conv_b = (const float*)d_in[5];
    const float* ln_g   = (const float*)d_in[6];
    const float* ln_b   = (const float*)d_in[7];
    const float* W_out  = (const float*)d_in[8];
    const float* b_out  = (const float*)d_in[9];
    float* out = (float*)d_out;
    char* ws = (char*)d_ws;

    int*            deg  = (int*)  (ws);
    int*            udeg = (int*)  (ws + (64 << 10));
    float*          dis  = (float*)(ws + (128 << 10));
    unsigned short* cols = (unsigned short*)(ws + (192 << 10));
    unsigned short* wbt  = (unsigned short*)(ws + (2u << 20));
    unsigned short* hA   = (unsigned short*)(ws + (2560u << 10));
    unsigned short* tbuf = (unsigned short*)(ws + (10752u << 10));
    unsigned short* hB   = (unsigned short*)d_out;     // d_out as bf16 scratch

    unsigned short* wbt_in   = wbt;
    unsigned short* wbt_conv = wbt + 32768;
    unsigned short* wbt_out  = wbt + 32768 + 196608;

    hipMemsetAsync(deg, 0, NN * 4, stream);
    k_w2bT <<<1024, 256, 0, stream>>>(W_in, conv_W, W_out, wbt);
    k_fill <<<NE / 256, 256, 0, stream>>>(ei, deg, cols);
    k_dedup<<<NN / 4, 256, 0, stream>>>(deg, cols, udeg, dis);

    // hB(d_out as bf16) = leaky(x @ W_in + b_in)   [fp32 A staged inline, K=128]
    k_gemm_mfma<256, 1, 1, 0, 0, 0><<<dim3(NN / 64, 1), 256, 0, stream>>>(
        nullptr, x, wbt_in, b_in, nullptr, nullptr, nullptr, nullptr, hB, NIN);

    unsigned short* hc = hB;
    unsigned short* hn = hA;
    for (int i = 0; i < 3; i++) {
        k_spmm_b<<<NN / 4, 256, 0, stream>>>(hc, udeg, cols, dis, tbuf);
        // hn = LN(leaky(tbuf @ conv_W[i] + conv_b[i]) + hc) * g + b   [fused]
        k_gemm_mfma<256, 0, 1, 1, 1, 0><<<dim3(NN / 64, 1), 256, 0, stream>>>(
            tbuf, nullptr, wbt_conv + (size_t)i * 65536, conv_b + (size_t)i * NHID,
            hc, ln_g + (size_t)i * NHID, ln_b + (size_t)i * NHID, nullptr, hn, NHID);
        unsigned short* tmp = hc; hc = hn; hn = tmp;
    }
    // final hc == hA; out = hc @ W_out + b_out (fp32, overwrites d_out)
    k_gemm_mfma<128, 0, 0, 0, 0, 1><<<dim3(NN / 64, 1), 256, 0, stream>>>(
        hc, nullptr, wbt_out, b_out, nullptr, nullptr, nullptr, out, nullptr, NHID);
}

// Round 13
// 235.682 us; speedup vs baseline: 1.0931x; 1.0931x over previous
//
#include <hip/hip_runtime.h>
#include <hip/hip_bf16.h>

#define NN 16384
#define NHID 256
#define NIN 128
#define NEMB 128
#define NE 262144
#define CAP 56   /* fixed neighbor capacity; P(overflow) ~ 1e-11 */

typedef short short8 __attribute__((ext_vector_type(8)));
typedef unsigned short ushort8 __attribute__((ext_vector_type(8)));
typedef float f32x4 __attribute__((ext_vector_type(4)));

__device__ __forceinline__ float b2f(unsigned short u) {
    return __uint_as_float(((unsigned)u) << 16);
}
__device__ __forceinline__ unsigned short f2b(float f) {
    __hip_bfloat16 h = __float2bfloat16(f);
    return *(unsigned short*)&h;
}
__device__ __forceinline__ unsigned pk2(float lo, float hi) {
    return ((unsigned)f2b(hi) << 16) | (unsigned)f2b(lo);
}
__device__ __forceinline__ bool detect_i64(const int* __restrict__ ei) {
    int any = 0;
    #pragma unroll
    for (int q = 0; q < 32; q++) any |= ei[2*q + 1];
    return any == 0;     // int64 layout: high words of first 32 entries all zero
}

// ---------------- weights -> bf16 transposed WbT[n][k] (one-time, 262144 elems) ----------------

__global__ __launch_bounds__(256) void k_w2bT(const float* __restrict__ W_in,
                                              const float* __restrict__ conv_W,
                                              const float* __restrict__ W_out,
                                              unsigned short* __restrict__ wbt) {
    int id = blockIdx.x * 256 + threadIdx.x;
    unsigned short* wbt_in   = wbt;                    // [256][128]
    unsigned short* wbt_conv = wbt + 32768;            // 3 x [256][256]
    unsigned short* wbt_out  = wbt + 32768 + 196608;   // [128][256]
    if (id < 32768) {              // W_in [128][256]
        int k = id >> 8, n = id & 255;
        wbt_in[n * NIN + k] = f2b(W_in[id]);
    } else if (id < 229376) {      // conv_W [3][256][256]
        int id2 = id - 32768;
        int l = id2 >> 16, r = id2 & 65535;
        int k = r >> 8, n = r & 255;
        wbt_conv[l * 65536 + n * NHID + k] = f2b(conv_W[id2]);
    } else {                       // W_out [256][128]
        int id2 = id - 229376;
        int k = id2 >> 7, n = id2 & 127;
        wbt_out[n * NHID + k] = f2b(W_out[id2]);
    }
}

// ---------------- graph build: fixed-capacity rows, slot = atomicAdd(deg) ----------------

__global__ void k_fill(const int* __restrict__ ei, int* __restrict__ deg,
                       unsigned short* __restrict__ cols) {
    bool i64 = detect_i64(ei);
    int e = blockIdx.x * 256 + threadIdx.x;
    if (e < NN) {
        int p = atomicAdd(&deg[e], 1);
        if (p < CAP) cols[e * CAP + p] = (unsigned short)e;
    }
    if (e >= NE) return;
    int r, c;
    if (i64) { r = ei[2*e]; c = ei[2*(NE + e)]; }
    else     { r = ei[e];   c = ei[NE + e]; }
    int p = atomicAdd(&deg[r], 1);
    if (p < CAP) cols[r * CAP + p] = (unsigned short)c;
}

// wave per row: in-register 64-lane bitonic sort + ballot compaction (proven R9-R12)
__global__ __launch_bounds__(256) void k_dedup(const int* __restrict__ deg,
                                               unsigned short* __restrict__ cols,
                                               int* __restrict__ udeg,
                                               float* __restrict__ dis) {
    int lane = threadIdx.x & 63;
    int row = (blockIdx.x * 256 + threadIdx.x) >> 6;
    int s = row * CAP;
    int L = deg[row]; if (L > CAP) L = CAP;
    int v = (lane < L) ? (int)cols[s + lane] : 0x7fffffff;
    #pragma unroll
    for (int k = 2; k <= 64; k <<= 1) {
        #pragma unroll
        for (int j = k >> 1; j > 0; j >>= 1) {
            int p = __shfl_xor(v, j);
            bool up = ((lane & k) == 0);
            bool keepmin = (((lane & j) == 0) == up);
            int lo = v < p ? v : p, hi = v < p ? p : v;
            v = keepmin ? lo : hi;
        }
    }
    int prev = __shfl_up(v, 1);
    bool keep = (lane < L) && !(lane > 0 && v == prev);
    unsigned long long km = __ballot(keep);
    int u = __popcll(km);
    int pre = __popcll(km & ((1ull << lane) - 1ull));
    if (keep) cols[s + pre] = (unsigned short)v;
    if (lane == 0) {
        udeg[row] = u;
        dis[row] = 1.0f / sqrtf((float)u + 1e-8f);
    }
}

// ---------------- SpMM: 2 neighbors/iter, 16B/lane, shfl_xor(32) combine ----------------

__global__ __launch_bounds__(256) void k_spmm_b(const unsigned short* __restrict__ h,
                                                const int* __restrict__ udeg,
                                                const unsigned short* __restrict__ cols,
                                                const float* __restrict__ dis,
                                                unsigned short* __restrict__ outb) {
    int row = (blockIdx.x * 256 + threadIdx.x) >> 6;
    int lane = threadIdx.x & 63;
    int half = lane >> 5, l32 = lane & 31;
    int s = row * CAP, L = udeg[row];
    float a[8] = {0.f, 0.f, 0.f, 0.f, 0.f, 0.f, 0.f, 0.f};
    for (int k = half; k < L; k += 2) {
        int j = cols[s + k];
        float sc = dis[j];
        ushort8 v = *(const ushort8*)&h[(size_t)j * NHID + l32 * 8];
        #pragma unroll
        for (int c = 0; c < 8; c++) a[c] += sc * b2f(v[c]);
    }
    #pragma unroll
    for (int c = 0; c < 8; c++) a[c] += __shfl_xor(a[c], 32);
    if (half == 0) {
        float sr = dis[row];
        ushort8 o;
        #pragma unroll
        for (int c = 0; c < 8; c++) o[c] = f2b(a[c] * sr);
        *(ushort8*)&outb[(size_t)row * NHID + l32 * 8] = o;
    }
}

// ---------------- MFMA bf16 GEMM (R11 geometry + bf16 WbT pure-copy B staging) ----------------
// Block tile 128 x (NT*32), 4 waves (2x2), wave tile 64 x (NT*16), BK=32.
// B from pre-transposed bf16 WbT[n][k]: thread copies 32/tpc contiguous k-elems of
// one col straight into Bs[col][k] (uint4 copies, zero conversion VALU).
// K-step prefetch: next step's global loads issue before current MFMA section.
// As[row][k] stride 40 bf16; Bs[col][k] stride 40.
// mfma_f32_16x16x32_bf16: A lane l -> A[row=l&15][k=(l>>4)*8+j]; B symmetric;
// D: col=lane&15, row=(lane>>4)*4+reg (m89-verified).

template<int NT, int AF32, int LEAKY, int RES, int OUTF32>
__global__ __launch_bounds__(256) void k_gemm_mfma(
        const unsigned short* __restrict__ Ab, const float* __restrict__ Af,
        const unsigned short* __restrict__ Wb,
        const float* __restrict__ bias, const unsigned short* __restrict__ res,
        float* __restrict__ outf, unsigned short* __restrict__ outb,
        int N, int K) {
    constexpr int C = NT * 32;               // block cols
    constexpr int TPC = 256 / C;             // threads per B col (2 for NT=4, 4 for NT=2)
    constexpr int NQ = NT / 2;               // uint4 loads per thread for B
    __shared__ unsigned short As[128 * 40];
    __shared__ unsigned short Bs[C * 40];
    int t = threadIdx.x;
    int lane = t & 63;
    int w = t >> 6;
    int wr = w >> 1, wc = w & 1;
    int bm0 = blockIdx.x * 128, bn0 = blockIdx.y * C;
    int lrow = lane & 15, lk8 = (lane >> 4) * 8;

    int ar = t >> 1, ah = t & 1;             // A staging: row 0..127, 16-elem half
    int bc = t / TPC, bks = (t % TPC) * (32 / TPC);  // B staging: col, k-slice start

    uint4 av0, av1;
    float4 xa0, xa1, xa2, xa3;
    uint4 bq[NQ];

    auto loadg = [&](int k0) {
        if (AF32) {
            const float* asrc = Af + (size_t)(bm0 + ar) * K + k0 + ah * 16;
            xa0 = *(const float4*)(asrc + 0);
            xa1 = *(const float4*)(asrc + 4);
            xa2 = *(const float4*)(asrc + 8);
            xa3 = *(const float4*)(asrc + 12);
        } else {
            const unsigned short* asrc = Ab + (size_t)(bm0 + ar) * K + k0 + ah * 16;
            av0 = *(const uint4*)asrc;
            av1 = *(const uint4*)(asrc + 8);
        }
        const unsigned short* bsrc = Wb + (size_t)(bn0 + bc) * K + k0 + bks;
        #pragma unroll
        for (int q = 0; q < NQ; q++) bq[q] = *(const uint4*)(bsrc + q * 8);
    };

    f32x4 acc[4][NT];
    #pragma unroll
    for (int m = 0; m < 4; m++)
        #pragma unroll
        for (int n = 0; n < NT; n++) acc[m][n] = (f32x4){0.f, 0.f, 0.f, 0.f};

    loadg(0);
    for (int k0 = 0; k0 < K; k0 += 32) {
        __syncthreads();                     // prior compute done before overwrite
        if (AF32) {
            unsigned* dst = (unsigned*)&As[ar * 40 + ah * 16];
            dst[0] = pk2(xa0.x, xa0.y); dst[1] = pk2(xa0.z, xa0.w);
            dst[2] = pk2(xa1.x, xa1.y); dst[3] = pk2(xa1.z, xa1.w);
            dst[4] = pk2(xa2.x, xa2.y); dst[5] = pk2(xa2.z, xa2.w);
            dst[6] = pk2(xa3.x, xa3.y); dst[7] = pk2(xa3.z, xa3.w);
        } else {
            *(uint4*)&As[ar * 40 + ah * 16]     = av0;
            *(uint4*)&As[ar * 40 + ah * 16 + 8] = av1;
        }
        #pragma unroll
        for (int q = 0; q < NQ; q++)
            *(uint4*)&Bs[bc * 40 + bks + q * 8] = bq[q];
        __syncthreads();
        if (k0 + 32 < K) loadg(k0 + 32);     // prefetch next step under compute
        short8 bf[NT];
        #pragma unroll
        for (int n = 0; n < NT; n++)
            bf[n] = *(const short8*)&Bs[(wc * (NT * 16) + n * 16 + lrow) * 40 + lk8];
        #pragma unroll
        for (int m = 0; m < 4; m++) {
            short8 af = *(const short8*)&As[(wr * 64 + m * 16 + lrow) * 40 + lk8];
            #pragma unroll
            for (int n = 0; n < NT; n++)
                acc[m][n] = __builtin_amdgcn_mfma_f32_16x16x32_bf16(af, bf[n], acc[m][n], 0, 0, 0);
        }
    }

    float bias_c[NT];
    #pragma unroll
    for (int n = 0; n < NT; n++) bias_c[n] = bias[bn0 + wc * (NT * 16) + n * 16 + lrow];

    #pragma unroll
    for (int m = 0; m < 4; m++) {
        #pragma unroll
        for (int n = 0; n < NT; n++) {
            int col = bn0 + wc * (NT * 16) + n * 16 + lrow;
            #pragma unroll
            for (int i = 0; i < 4; i++) {
                int row = bm0 + wr * 64 + m * 16 + (lane >> 4) * 4 + i;
                float v = acc[m][n][i] + bias_c[n];
                if (LEAKY) v = v > 0.f ? v : 0.2f * v;
                if (RES) v += b2f(res[(size_t)row * N + col]);
                if (OUTF32) outf[(size_t)row * N + col] = v;
                else        outb[(size_t)row * N + col] = f2b(v);
            }
        }
    }
}

// ---------------- LayerNorm (bf16 in/out, fp32 stats, wave per row; proven R8-R11) ----------------

__global__ __launch_bounds__(256) void k_ln_b(unsigned short* __restrict__ h,
                                              const float* __restrict__ g,
                                              const float* __restrict__ b) {
    int row = (blockIdx.x * 256 + threadIdx.x) >> 6;
    int lane = threadIdx.x & 63;
    ushort4 v = *(ushort4*)&h[(size_t)row * NHID + lane * 4];
    float f0 = b2f(v.x), f1 = b2f(v.y), f2 = b2f(v.z), f3 = b2f(v.w);
    float s = f0 + f1 + f2 + f3;
    for (int off = 32; off; off >>= 1) s += __shfl_xor(s, off);
    float mean = s * (1.0f / 256.0f);
    float d0 = f0 - mean, d1 = f1 - mean, d2 = f2 - mean, d3 = f3 - mean;
    float ss = d0 * d0 + d1 * d1 + d2 * d2 + d3 * d3;
    for (int off = 32; off; off >>= 1) ss += __shfl_xor(ss, off);
    float rstd = 1.0f / sqrtf(ss * (1.0f / 256.0f) + 1e-5f);
    float4 gg = ((const float4*)g)[lane];
    float4 bb = ((const float4*)b)[lane];
    ushort4 o;
    o.x = f2b(d0 * rstd * gg.x + bb.x);
    o.y = f2b(d1 * rstd * gg.y + bb.y);
    o.z = f2b(d2 * rstd * gg.z + bb.z);
    o.w = f2b(d3 * rstd * gg.w + bb.w);
    *(ushort4*)&h[(size_t)row * NHID + lane * 4] = o;
}

// ---------------- launch ----------------
// ws layout (~18.6 MB): deg @0 (64K), udeg @64K, dis @128K, cols @192K (1.75 MB),
//   WbT @2MB (512 KB), hA @2.5MB (8 MB) -> 10.5MB, tbuf @10.5MB (8 MB) -> 18.5MB.
//   hB = d_out as bf16 scratch; final GEMM reads hA, writes d_out fp32.

extern "C" void kernel_launch(void* const* d_in, const int* in_sizes, int n_in,
                              void* d_out, int out_size, void* d_ws, size_t ws_size,
                              hipStream_t stream) {
    const float* x      = (const float*)d_in[0];
    const int*   ei     = (const int*)  d_in[1];
    const float* W_in   = (const float*)d_in[2];
    const float* b_in   = (const float*)d_in[3];
    const float* conv_W = (const float*)d_in[4];
    const float* conv_b = (const float*)d_in[5];
    const float* ln_g   = (const float*)d_in[6];
    const float* ln_b   = (const float*)d_in[7];
    const float* W_out  = (const float*)d_in[8];
    const float* b_out  = (const float*)d_in[9];
    float* out = (float*)d_out;
    char* ws = (char*)d_ws;

    int*            deg  = (int*)  (ws);
    int*            udeg = (int*)  (ws + (64 << 10));
    float*          dis  = (float*)(ws + (128 << 10));
    unsigned short* cols = (unsigned short*)(ws + (192 << 10));
    unsigned short* wbt  = (unsigned short*)(ws + (2u << 20));
    unsigned short* hA   = (unsigned short*)(ws + (2560u << 10));
    unsigned short* tbuf = (unsigned short*)(ws + (10752u << 10));
    unsigned short* hB   = (unsigned short*)d_out;     // d_out as bf16 scratch

    unsigned short* wbt_in   = wbt;
    unsigned short* wbt_conv = wbt + 32768;
    unsigned short* wbt_out  = wbt + 32768 + 196608;

    hipMemsetAsync(deg, 0, NN * 4, stream);
    k_w2bT <<<1024, 256, 0, stream>>>(W_in, conv_W, W_out, wbt);
    k_fill <<<NE / 256, 256, 0, stream>>>(ei, deg, cols);
    k_dedup<<<NN / 4, 256, 0, stream>>>(deg, cols, udeg, dis);

    // hB(d_out as bf16) = leaky(x @ W_in + b_in)   [fp32 A staged inline, K=128]
    k_gemm_mfma<4, 1, 1, 0, 0><<<dim3(NN / 128, NHID / 128), 256, 0, stream>>>(
        nullptr, x, wbt_in, b_in, nullptr, nullptr, hB, NHID, NIN);

    unsigned short* hc = hB;
    unsigned short* hn = hA;
    for (int i = 0; i < 3; i++) {
        k_spmm_b<<<NN / 4, 256, 0, stream>>>(hc, udeg, cols, dis, tbuf);
        k_gemm_mfma<4, 0, 1, 1, 0><<<dim3(NN / 128, NHID / 128), 256, 0, stream>>>(
            tbuf, nullptr, wbt_conv + (size_t)i * 65536, conv_b + (size_t)i * NHID,
            hc, nullptr, hn, NHID, NHID);
        k_ln_b<<<NN / 4, 256, 0, stream>>>(hn, ln_g + (size_t)i * NHID, ln_b + (size_t)i * NHID);
        unsigned short* tmp = hc; hc = hn; hn = tmp;
    }
    // final hc == hA; out = hc @ W_out + b_out (fp32, overwrites d_out)
    k_gemm_mfma<2, 0, 0, 0, 1><<<dim3(NN / 128, NEMB / 64), 256, 0, stream>>>(
        hc, nullptr, wbt_out, b_out, nullptr, out, nullptr, NEMB, NHID);
}